// Round 8
// baseline (210.593 us; speedup 1.0000x reference)
//
#include <hip/hip_runtime.h>

#define EPSV 1e-5f
constexpr int Bb = 4, Cc = 64, Nn = 40960, Kk = 16, Dd = 128;
constexpr int G = 4;                       // point-tiles per block in pass B (even!)
constexpr int TPB = Nn / 16;               // tiles per batch = 2560

typedef float f32x4 __attribute__((ext_vector_type(4)));
typedef __bf16 bf16x8 __attribute__((ext_vector_type(8)));
typedef unsigned short us8 __attribute__((ext_vector_type(8)));
typedef unsigned short us4 __attribute__((ext_vector_type(4)));

__device__ inline unsigned short f2bf(float x) {
    unsigned u = __builtin_bit_cast(unsigned, x);
    u += 0x7FFFu + ((u >> 16) & 1u);   // RNE
    return (unsigned short)(u >> 16);
}

// ---------------------------------------------------------------------------
// Prep: fold BN scale into bf16 weights, precompute shifts.
__global__ __launch_bounds__(256) void prep_weights(
    const float* __restrict__ w1, const float* __restrict__ g1, const float* __restrict__ b1,
    const float* __restrict__ m1, const float* __restrict__ v1,
    const float* __restrict__ w2, const float* __restrict__ g2, const float* __restrict__ b2,
    const float* __restrict__ m2, const float* __restrict__ v2,
    const float* __restrict__ w3, const float* __restrict__ g3, const float* __restrict__ b3,
    const float* __restrict__ m3, const float* __restrict__ v3,
    unsigned short* __restrict__ w1s, unsigned short* __restrict__ w2s, unsigned short* __restrict__ w3s,
    float* __restrict__ sh1, float* __restrict__ sh2, float* __restrict__ sh3) {
    const int e = blockIdx.x * 256 + threadIdx.x;
    if (e < 4096) {
        const int o = e >> 6;
        const float sc = g1[o] * rsqrtf(v1[o] + EPSV);
        w1s[e] = f2bf(w1[e] * sc);
    } else if (e < 12288) {
        const int i = e - 4096, o = i >> 6;
        const float sc = g2[o] * rsqrtf(v2[o] + EPSV);
        w2s[i] = f2bf(w2[i] * sc);
    } else if (e < 20480) {
        const int i = e - 12288, o = i >> 6;
        const float sc = g3[o] * rsqrtf(v3[o] + EPSV);
        w3s[i] = f2bf(w3[i] * sc);
    }
    if (e < 64) sh1[e] = b1[e] - m1[e] * (g1[e] * rsqrtf(v1[e] + EPSV));
    else if (e < 192) { const int d = e - 64;  sh2[d] = b2[d] - m2[d] * (g2[d] * rsqrtf(v2[d] + EPSV)); }
    else if (e < 320) { const int d = e - 192; sh3[d] = b3[d] - m3[d] * (g3[d] * rsqrtf(v3[d] + EPSV)); }
}

// ---------------------------------------------------------------------------
// Pass A v2: G1 = relu(sc1*(W1.f) + sh1) -> (B,N,64) bf16, plus f_t frags.
// TRANSPOSE-FREE: A = weights (rows = out-ch), B = f (cols = points), so the
// B-frag is 16 coalesced strided loads (64-B segments) + 16 f2bf per thread —
// no LDS input tile, no 64 ds_read + 64 cvt. The f B-frag IS the f_t
// fragment (same lane->elem layout), stored directly. One barrier total
// (output-staging transpose for the coalesced G1 store).
__global__ __launch_bounds__(256) void passA(const float* __restrict__ f,
                                             const unsigned short* __restrict__ w1s,
                                             const float* __restrict__ sh1,
                                             unsigned short* __restrict__ G1,
                                             unsigned short* __restrict__ f_t) {
    __shared__ __attribute__((aligned(16))) unsigned short sg1[64 * 72];  // [pt][ch]

    const int tid = threadIdx.x, w = tid >> 6, lane = tid & 63;
    const int c15 = lane & 15, q = lane >> 4;
    const int b = blockIdx.x / 640;
    const int n0 = (blockIdx.x % 640) * 64;
    const int p  = n0 + w * 16 + c15;       // this thread's point (MFMA B-col)

    // f B-frags: k = ch = ks*32 + q*8 + j, col = point p. Lanes 0-15 read
    // consecutive points -> 64-B coalesced segments; adjacent waves complete
    // each 128-B line.
    const float* fp = f + (size_t)b * Cc * Nn + p;
    us8 F0, F1;
#pragma unroll
    for (int j = 0; j < 8; ++j) F0[j] = f2bf(fp[(size_t)(q * 8 + j) * Nn]);
#pragma unroll
    for (int j = 0; j < 8; ++j) F1[j] = f2bf(fp[(size_t)(32 + q * 8 + j) * Nn]);

    // f_t store: this thread's frags are exactly f_t[p][q*8..] / [32+q*8..]
    {
        unsigned short* dst = f_t + ((size_t)b * Nn + p) * 64 + q * 8;
        *(uint4*)dst        = __builtin_bit_cast(uint4, F0);
        *(uint4*)(dst + 32) = __builtin_bit_cast(uint4, F1);
    }

    const bf16x8 bf0 = __builtin_bit_cast(bf16x8, F0);
    const bf16x8 bf1 = __builtin_bit_cast(bf16x8, F1);

    // D[o][p]: row o = nt*16 + q*4 + r, col = c15 (point). Weight A-frag:
    // row o' = nt*16 + c15, k contiguous -> uint4 loads from pre-scaled w1s.
#pragma unroll
    for (int nt = 0; nt < 4; ++nt) {
        const int oa = nt * 16 + c15;
        const bf16x8 aw0 = __builtin_bit_cast(bf16x8, *(const uint4*)(w1s + oa * 64 + q * 8));
        const bf16x8 aw1 = __builtin_bit_cast(bf16x8, *(const uint4*)(w1s + oa * 64 + 32 + q * 8));
        f32x4 acc = {0.f, 0.f, 0.f, 0.f};
        acc = __builtin_amdgcn_mfma_f32_16x16x32_bf16(aw0, bf0, acc, 0, 0, 0);
        acc = __builtin_amdgcn_mfma_f32_16x16x32_bf16(aw1, bf1, acc, 0, 0, 0);
        const f32x4 shv = *(const f32x4*)(sh1 + nt * 16 + q * 4);
#pragma unroll
        for (int r = 0; r < 4; ++r)
            sg1[(w * 16 + c15) * 72 + nt * 16 + q * 4 + r] = f2bf(fmaxf(acc[r] + shv[r], 0.f));
    }
    __syncthreads();

    // coalesced store: thread (pt = tid>>2, ck = tid&3) writes 32 B of row pt
    {
        const int pt = tid >> 2, ck = tid & 3;
        const uint4 v0 = *(const uint4*)(sg1 + pt * 72 + ck * 16);
        const uint4 v1 = *(const uint4*)(sg1 + pt * 72 + ck * 16 + 8);
        unsigned short* dst = G1 + ((size_t)b * Nn + n0 + pt) * 64 + ck * 16;
        *(uint4*)dst = v0;
        *(uint4*)(dst + 8) = v1;
    }
}

// ---------------------------------------------------------------------------
// Pass B (round-5 validated skeleton) with DOUBLE-BUFFERED s_h1:
// per tile g: gather -> write s_h1[g&1] -> sync -> MFMA; +1 sync per pair for
// the full-line store. 6 barriers per 4-tile group (was 12). The g+1 gather's
// global loads now issue with no barrier after MFMA(g) -> latency overlap.
// Hazard audit: s_h1[buf] reuse (g vs g-2) fenced by the intervening sync;
// s_out row-half reuse fenced by the pre-MFMA sync after each pair's store.
__global__ __launch_bounds__(256, 4) void passB(
    const unsigned short* __restrict__ G1, const unsigned short* __restrict__ f_t,
    const int* __restrict__ idx,
    const unsigned short* __restrict__ w2s, const unsigned short* __restrict__ w3s,
    const float* __restrict__ sh2, const float* __restrict__ sh3,
    float* __restrict__ out) {
    __shared__ __attribute__((aligned(16))) unsigned short s_h1[2][16 * 72]; // 4608 B
    __shared__ float s_out[32 * 133];                                        // 17024 B

    const int tid  = threadIdx.x;
    const int wave = tid >> 6;
    const int lane = tid & 63;
    const int c15  = lane & 15;
    const int q    = lane >> 4;
    const int pg   = tid >> 4;              // gather-phase point 0..15
    const int cg   = tid & 15;              // gather-phase channel group (4 ch)

    // XCD-batch affinity (dispatch round-robins blockIdx over the 8 XCDs)
    const int xcd = blockIdx.x & 7;
    const int jb  = blockIdx.x >> 3;        // 0..319
    const int b   = xcd >> 1;               // 2 XCDs per batch -> G1 ~L2-resident
    const int nb0 = (((xcd & 1) * 320) + jb) * (G * 16);

    // weight B-frags (register-resident, bf16 pre-scaled)
    float sh2v[2], sh3v[2];
    bf16x8 bw2[2][2], bw3[2][2];
#pragma unroll
    for (int nt = 0; nt < 2; ++nt) {
        const int d = wave * 32 + nt * 16 + c15;
        sh2v[nt] = sh2[d];
        sh3v[nt] = sh3[d];
#pragma unroll
        for (int ks = 0; ks < 2; ++ks) {
            bw2[nt][ks] = __builtin_bit_cast(bf16x8, *(const uint4*)(w2s + d * 64 + ks * 32 + q * 8));
            bw3[nt][ks] = __builtin_bit_cast(bf16x8, *(const uint4*)(w3s + d * 64 + ks * 32 + q * 8));
        }
    }

    const unsigned short* G1b = G1 + (size_t)b * Nn * 64;
    const unsigned short* ftb = f_t + (size_t)b * Nn * 64;
    const int* idxp = idx + ((size_t)b * Nn + nb0) * Kk;

    int myidx = idxp[tid];                  // tile 0's idx row

    for (int g = 0; g < G; ++g) {
        const int n0 = nb0 + g * 16;

        // prefetch next tile's idx row
        const int myidxN = (g + 1 < G) ? idxp[(g + 1) * 256 + tid] : 0;

        // skip-path A-frags: contiguous bf16 rows from f_t
        const unsigned short* ftrow = ftb + (size_t)(n0 + c15) * 64;
        const bf16x8 af0 = __builtin_bit_cast(bf16x8, *(const uint4*)(ftrow + q * 8));
        const bf16x8 af1 = __builtin_bit_cast(bf16x8, *(const uint4*)(ftrow + 32 + q * 8));

        // gather + sum (G1 rows pre-relu'd -> pure adds)
        float a0 = 0.f, a1 = 0.f, a2 = 0.f, a3 = 0.f;
#pragma unroll
        for (int k = 0; k < 16; ++k) {
            const int nb = __shfl(myidx, (pg & 3) * 16 + k, 64);
            const uint2 d2 = *(const uint2*)(G1b + (size_t)nb * 64 + cg * 4);
            a0 += __builtin_bit_cast(float, d2.x << 16);
            a1 += __builtin_bit_cast(float, d2.x & 0xffff0000u);
            a2 += __builtin_bit_cast(float, d2.y << 16);
            a3 += __builtin_bit_cast(float, d2.y & 0xffff0000u);
        }
        myidx = myidxN;

        // h1 -> LDS (double buffer: no wait on prev tile's MFMA reads)
        {
            us4 hv;
            hv[0] = f2bf(a0); hv[1] = f2bf(a1); hv[2] = f2bf(a2); hv[3] = f2bf(a3);
            *(us4*)(&s_h1[g & 1][0] + pg * 72 + cg * 4) = hv;
        }
        __syncthreads();                     // s_h1[g&1] complete (also fences
                                             // prior store reads / buf reuse)

        // GEMM2 (W2 . h1) + skip (W3 . f_own)
        const unsigned short* h1row = &s_h1[g & 1][0] + c15 * 72;
        const bf16x8 ah0 = __builtin_bit_cast(bf16x8, *(const uint4*)(h1row + q * 8));
        const bf16x8 ah1 = __builtin_bit_cast(bf16x8, *(const uint4*)(h1row + 32 + q * 8));

        const int prow = (g & 1) * 16;       // s_out row base for this tile
#pragma unroll
        for (int nt = 0; nt < 2; ++nt) {
            f32x4 h2 = {sh2v[nt], sh2v[nt], sh2v[nt], sh2v[nt]};
            f32x4 s3 = {sh3v[nt], sh3v[nt], sh3v[nt], sh3v[nt]};
            h2 = __builtin_amdgcn_mfma_f32_16x16x32_bf16(ah0, bw2[nt][0], h2, 0, 0, 0);
            h2 = __builtin_amdgcn_mfma_f32_16x16x32_bf16(ah1, bw2[nt][1], h2, 0, 0, 0);
            s3 = __builtin_amdgcn_mfma_f32_16x16x32_bf16(af0, bw3[nt][0], s3, 0, 0, 0);
            s3 = __builtin_amdgcn_mfma_f32_16x16x32_bf16(af1, bw3[nt][1], s3, 0, 0, 0);
            const int d = wave * 32 + nt * 16 + c15;
#pragma unroll
            for (int r = 0; r < 4; ++r)
                s_out[(prow + q * 4 + r) * 133 + d] = fmaxf(h2[r], 0.f) + fmaxf(s3[r], 0.f);
        }

        // full-line nontemporal store every 2 tiles
        if (g & 1) {
            __syncthreads();                 // all 32 s_out rows visible
            const int np = n0 - 16;          // pair base point (line-aligned)
            const int dd = tid >> 3;         // 0..31: row within pass
            const int ck = tid & 7;          // 16-B chunk within line
#pragma unroll
            for (int r4 = 0; r4 < 4; ++r4) {
                const int d = r4 * 32 + dd;
                f32x4 v;
#pragma unroll
                for (int i = 0; i < 4; ++i) v[i] = s_out[(ck * 4 + i) * 133 + d];
                __builtin_nontemporal_store(v, (f32x4*)(out + ((size_t)b * Dd + d) * Nn + np + ck * 4));
            }
        }
    }
}

extern "C" void kernel_launch(void* const* d_in, const int* in_sizes, int n_in,
                              void* d_out, int out_size, void* d_ws, size_t ws_size,
                              hipStream_t stream) {
    const float* feature = (const float*)d_in[0];
    const int*   neigh   = (const int*)d_in[1];
    const float* w1 = (const float*)d_in[2];
    const float* g1 = (const float*)d_in[3];
    const float* b1 = (const float*)d_in[4];
    const float* m1 = (const float*)d_in[5];
    const float* v1 = (const float*)d_in[6];
    const float* w2 = (const float*)d_in[7];
    const float* g2 = (const float*)d_in[8];
    const float* b2 = (const float*)d_in[9];
    const float* m2 = (const float*)d_in[10];
    const float* v2 = (const float*)d_in[11];
    const float* w3 = (const float*)d_in[12];
    const float* g3 = (const float*)d_in[13];
    const float* b3 = (const float*)d_in[14];
    const float* m3 = (const float*)d_in[15];
    const float* v3 = (const float*)d_in[16];
    float* out = (float*)d_out;

    const size_t SZ_G1 = (size_t)Bb * Nn * 64 * 2;        // 20,971,520 B
    const size_t SZ_FT = (size_t)Bb * Nn * 64 * 2;        // 20,971,520 B

    char* ws = (char*)d_ws;
    unsigned short* G1  = (unsigned short*)ws;
    unsigned short* f_t = (unsigned short*)(ws + SZ_G1);
    char* wbase = ws + SZ_G1 + SZ_FT;

    unsigned short* w1s = (unsigned short*)wbase;
    unsigned short* w2s = (unsigned short*)(wbase + 8192);
    unsigned short* w3s = (unsigned short*)(wbase + 24576);
    float* sh1 = (float*)(wbase + 40960);
    float* sh2 = (float*)(wbase + 41216);
    float* sh3 = (float*)(wbase + 41728);

    prep_weights<<<80, 256, 0, stream>>>(w1, g1, b1, m1, v1, w2, g2, b2, m2, v2,
                                         w3, g3, b3, m3, v3, w1s, w2s, w3s, sh1, sh2, sh3);
    passA<<<Bb * 640, 256, 0, stream>>>(feature, w1s, sh1, G1, f_t);
    passB<<<(Bb * TPB) / G, 256, 0, stream>>>(G1, f_t, neigh, w2s, w3s,
                                              sh2, sh3, out);
}

// Round 9
// 208.421 us; speedup vs baseline: 1.0104x; 1.0104x over previous
//
#include <hip/hip_runtime.h>

#define EPSV 1e-5f
constexpr int Bb = 4, Cc = 64, Nn = 40960, Kk = 16, Dd = 128;
constexpr int G = 4;                       // point-tiles per block in pass B (even!)
constexpr int TPB = Nn / 16;               // tiles per batch = 2560

typedef float f32x4 __attribute__((ext_vector_type(4)));
typedef __bf16 bf16x8 __attribute__((ext_vector_type(8)));
typedef unsigned short us8 __attribute__((ext_vector_type(8)));
typedef unsigned short us4 __attribute__((ext_vector_type(4)));

__device__ inline unsigned short f2bf(float x) {
    unsigned u = __builtin_bit_cast(unsigned, x);
    u += 0x7FFFu + ((u >> 16) & 1u);   // RNE
    return (unsigned short)(u >> 16);
}

// ---------------------------------------------------------------------------
// Prep: fold BN scale into bf16 weights, precompute shifts.
__global__ __launch_bounds__(256) void prep_weights(
    const float* __restrict__ w1, const float* __restrict__ g1, const float* __restrict__ b1,
    const float* __restrict__ m1, const float* __restrict__ v1,
    const float* __restrict__ w2, const float* __restrict__ g2, const float* __restrict__ b2,
    const float* __restrict__ m2, const float* __restrict__ v2,
    const float* __restrict__ w3, const float* __restrict__ g3, const float* __restrict__ b3,
    const float* __restrict__ m3, const float* __restrict__ v3,
    unsigned short* __restrict__ w1s, unsigned short* __restrict__ w2s, unsigned short* __restrict__ w3s,
    float* __restrict__ sh1, float* __restrict__ sh2, float* __restrict__ sh3) {
    const int e = blockIdx.x * 256 + threadIdx.x;
    if (e < 4096) {
        const int o = e >> 6;
        const float sc = g1[o] * rsqrtf(v1[o] + EPSV);
        w1s[e] = f2bf(w1[e] * sc);
    } else if (e < 12288) {
        const int i = e - 4096, o = i >> 6;
        const float sc = g2[o] * rsqrtf(v2[o] + EPSV);
        w2s[i] = f2bf(w2[i] * sc);
    } else if (e < 20480) {
        const int i = e - 12288, o = i >> 6;
        const float sc = g3[o] * rsqrtf(v3[o] + EPSV);
        w3s[i] = f2bf(w3[i] * sc);
    }
    if (e < 64) sh1[e] = b1[e] - m1[e] * (g1[e] * rsqrtf(v1[e] + EPSV));
    else if (e < 192) { const int d = e - 64;  sh2[d] = b2[d] - m2[d] * (g2[d] * rsqrtf(v2[d] + EPSV)); }
    else if (e < 320) { const int d = e - 192; sh3[d] = b3[d] - m3[d] * (g3[d] * rsqrtf(v3[d] + EPSV)); }
}

// ---------------------------------------------------------------------------
// Pass A v3: G1 = relu(sc1*(W1.f) + sh1) -> (B,N,64) bf16, plus f_t frags.
// v1's coalesced global->LDS staging (256-B contiguous per wave-instruction;
// v2's direct-global B-frags scattered 4x64-B segments and regressed ~7us)
// + v2's operand swap (A = weights, B = f-columns): the per-thread fragment
// phase is 16 ds_read + 16 f2bf (one point's channel column; bank aliasing
// exactly 2-way = free) instead of v1's 64 ds_read + 64 f2bf.
// The B-frag IS the f_t fragment -> stored directly.
__global__ __launch_bounds__(256) void passA(const float* __restrict__ f,
                                             const unsigned short* __restrict__ w1s,
                                             const float* __restrict__ sh1,
                                             unsigned short* __restrict__ G1,
                                             unsigned short* __restrict__ f_t) {
    __shared__ float s[64 * 65];                            // [ch][pt]
    __shared__ __attribute__((aligned(16))) unsigned short sg1[64 * 72];  // [pt][ch]

    const int tid = threadIdx.x, w = tid >> 6, lane = tid & 63;
    const int c15 = lane & 15, q = lane >> 4;
    const int b = blockIdx.x / 640;
    const int n0 = (blockIdx.x % 640) * 64;

    // stage fp32 tile [64 ch][64 pts]: 256-B contiguous per wave-instruction
    const float* src = f + ((size_t)b * Cc + w * 16) * Nn + n0 + lane;
#pragma unroll
    for (int i = 0; i < 16; ++i) s[(w * 16 + i) * 65 + lane] = src[(size_t)i * Nn];
    __syncthreads();

    // B-frag: this thread's point ptl = w*16+c15, channels q*8+j / 32+q*8+j.
    // bank = (ch*65 + ptl) mod 32 = (8q + j + ptl) mod 32 -> 2-way aliasing.
    const int ptl = w * 16 + c15;
    us8 F0, F1;
#pragma unroll
    for (int j = 0; j < 8; ++j) F0[j] = f2bf(s[(q * 8 + j) * 65 + ptl]);
#pragma unroll
    for (int j = 0; j < 8; ++j) F1[j] = f2bf(s[(32 + q * 8 + j) * 65 + ptl]);

    // f_t store: frags are exactly f_t[p][q*8..] / [32+q*8..]
    {
        unsigned short* dst = f_t + ((size_t)b * Nn + n0 + ptl) * 64;
        *(uint4*)(dst + q * 8)      = __builtin_bit_cast(uint4, F0);
        *(uint4*)(dst + 32 + q * 8) = __builtin_bit_cast(uint4, F1);
    }

    const bf16x8 bf0 = __builtin_bit_cast(bf16x8, F0);
    const bf16x8 bf1 = __builtin_bit_cast(bf16x8, F1);

    // D[o][pt]: A = pre-scaled weight rows (k contiguous -> uint4 from w1s),
    // B = f columns. Lane (c15,q) reg r holds D[nt*16+q*4+r][ptl].
#pragma unroll
    for (int nt = 0; nt < 4; ++nt) {
        const int oa = nt * 16 + c15;
        const bf16x8 aw0 = __builtin_bit_cast(bf16x8, *(const uint4*)(w1s + oa * 64 + q * 8));
        const bf16x8 aw1 = __builtin_bit_cast(bf16x8, *(const uint4*)(w1s + oa * 64 + 32 + q * 8));
        f32x4 acc = {0.f, 0.f, 0.f, 0.f};
        acc = __builtin_amdgcn_mfma_f32_16x16x32_bf16(aw0, bf0, acc, 0, 0, 0);
        acc = __builtin_amdgcn_mfma_f32_16x16x32_bf16(aw1, bf1, acc, 0, 0, 0);
        const f32x4 shv = *(const f32x4*)(sh1 + nt * 16 + q * 4);
#pragma unroll
        for (int r = 0; r < 4; ++r)
            sg1[ptl * 72 + nt * 16 + q * 4 + r] = f2bf(fmaxf(acc[r] + shv[r], 0.f));
    }
    __syncthreads();

    // coalesced store: thread (pt = tid>>2, ck = tid&3) writes 32 B of row pt
    {
        const int pt = tid >> 2, ck = tid & 3;
        const uint4 v0 = *(const uint4*)(sg1 + pt * 72 + ck * 16);
        const uint4 v1 = *(const uint4*)(sg1 + pt * 72 + ck * 16 + 8);
        unsigned short* dst = G1 + ((size_t)b * Nn + n0 + pt) * 64 + ck * 16;
        *(uint4*)dst = v0;
        *(uint4*)(dst + 8) = v1;
    }
}

// ---------------------------------------------------------------------------
// Pass B — byte-identical to round 8 (validated 61.6us profiled):
// double-buffered s_h1, 6 barriers per 4-tile group, XCD-batch affinity,
// f_t skip-path frags, pair-buffered full-128B-line nt-store epilogue.
__global__ __launch_bounds__(256, 4) void passB(
    const unsigned short* __restrict__ G1, const unsigned short* __restrict__ f_t,
    const int* __restrict__ idx,
    const unsigned short* __restrict__ w2s, const unsigned short* __restrict__ w3s,
    const float* __restrict__ sh2, const float* __restrict__ sh3,
    float* __restrict__ out) {
    __shared__ __attribute__((aligned(16))) unsigned short s_h1[2][16 * 72]; // 4608 B
    __shared__ float s_out[32 * 133];                                        // 17024 B

    const int tid  = threadIdx.x;
    const int wave = tid >> 6;
    const int lane = tid & 63;
    const int c15  = lane & 15;
    const int q    = lane >> 4;
    const int pg   = tid >> 4;              // gather-phase point 0..15
    const int cg   = tid & 15;              // gather-phase channel group (4 ch)

    // XCD-batch affinity (dispatch round-robins blockIdx over the 8 XCDs)
    const int xcd = blockIdx.x & 7;
    const int jb  = blockIdx.x >> 3;        // 0..319
    const int b   = xcd >> 1;               // 2 XCDs per batch -> G1 ~L2-resident
    const int nb0 = (((xcd & 1) * 320) + jb) * (G * 16);

    // weight B-frags (register-resident, bf16 pre-scaled)
    float sh2v[2], sh3v[2];
    bf16x8 bw2[2][2], bw3[2][2];
#pragma unroll
    for (int nt = 0; nt < 2; ++nt) {
        const int d = wave * 32 + nt * 16 + c15;
        sh2v[nt] = sh2[d];
        sh3v[nt] = sh3[d];
#pragma unroll
        for (int ks = 0; ks < 2; ++ks) {
            bw2[nt][ks] = __builtin_bit_cast(bf16x8, *(const uint4*)(w2s + d * 64 + ks * 32 + q * 8));
            bw3[nt][ks] = __builtin_bit_cast(bf16x8, *(const uint4*)(w3s + d * 64 + ks * 32 + q * 8));
        }
    }

    const unsigned short* G1b = G1 + (size_t)b * Nn * 64;
    const unsigned short* ftb = f_t + (size_t)b * Nn * 64;
    const int* idxp = idx + ((size_t)b * Nn + nb0) * Kk;

    int myidx = idxp[tid];                  // tile 0's idx row

    for (int g = 0; g < G; ++g) {
        const int n0 = nb0 + g * 16;

        // prefetch next tile's idx row
        const int myidxN = (g + 1 < G) ? idxp[(g + 1) * 256 + tid] : 0;

        // skip-path A-frags: contiguous bf16 rows from f_t
        const unsigned short* ftrow = ftb + (size_t)(n0 + c15) * 64;
        const bf16x8 af0 = __builtin_bit_cast(bf16x8, *(const uint4*)(ftrow + q * 8));
        const bf16x8 af1 = __builtin_bit_cast(bf16x8, *(const uint4*)(ftrow + 32 + q * 8));

        // gather + sum (G1 rows pre-relu'd -> pure adds)
        float a0 = 0.f, a1 = 0.f, a2 = 0.f, a3 = 0.f;
#pragma unroll
        for (int k = 0; k < 16; ++k) {
            const int nb = __shfl(myidx, (pg & 3) * 16 + k, 64);
            const uint2 d2 = *(const uint2*)(G1b + (size_t)nb * 64 + cg * 4);
            a0 += __builtin_bit_cast(float, d2.x << 16);
            a1 += __builtin_bit_cast(float, d2.x & 0xffff0000u);
            a2 += __builtin_bit_cast(float, d2.y << 16);
            a3 += __builtin_bit_cast(float, d2.y & 0xffff0000u);
        }
        myidx = myidxN;

        // h1 -> LDS (double buffer: no wait on prev tile's MFMA reads)
        {
            us4 hv;
            hv[0] = f2bf(a0); hv[1] = f2bf(a1); hv[2] = f2bf(a2); hv[3] = f2bf(a3);
            *(us4*)(&s_h1[g & 1][0] + pg * 72 + cg * 4) = hv;
        }
        __syncthreads();                     // s_h1[g&1] complete (also fences
                                             // prior store reads / buf reuse)

        // GEMM2 (W2 . h1) + skip (W3 . f_own)
        const unsigned short* h1row = &s_h1[g & 1][0] + c15 * 72;
        const bf16x8 ah0 = __builtin_bit_cast(bf16x8, *(const uint4*)(h1row + q * 8));
        const bf16x8 ah1 = __builtin_bit_cast(bf16x8, *(const uint4*)(h1row + 32 + q * 8));

        const int prow = (g & 1) * 16;       // s_out row base for this tile
#pragma unroll
        for (int nt = 0; nt < 2; ++nt) {
            f32x4 h2 = {sh2v[nt], sh2v[nt], sh2v[nt], sh2v[nt]};
            f32x4 s3 = {sh3v[nt], sh3v[nt], sh3v[nt], sh3v[nt]};
            h2 = __builtin_amdgcn_mfma_f32_16x16x32_bf16(ah0, bw2[nt][0], h2, 0, 0, 0);
            h2 = __builtin_amdgcn_mfma_f32_16x16x32_bf16(ah1, bw2[nt][1], h2, 0, 0, 0);
            s3 = __builtin_amdgcn_mfma_f32_16x16x32_bf16(af0, bw3[nt][0], s3, 0, 0, 0);
            s3 = __builtin_amdgcn_mfma_f32_16x16x32_bf16(af1, bw3[nt][1], s3, 0, 0, 0);
            const int d = wave * 32 + nt * 16 + c15;
#pragma unroll
            for (int r = 0; r < 4; ++r)
                s_out[(prow + q * 4 + r) * 133 + d] = fmaxf(h2[r], 0.f) + fmaxf(s3[r], 0.f);
        }

        // full-line nontemporal store every 2 tiles
        if (g & 1) {
            __syncthreads();                 // all 32 s_out rows visible
            const int np = n0 - 16;          // pair base point (line-aligned)
            const int dd = tid >> 3;         // 0..31: row within pass
            const int ck = tid & 7;          // 16-B chunk within line
#pragma unroll
            for (int r4 = 0; r4 < 4; ++r4) {
                const int d = r4 * 32 + dd;
                f32x4 v;
#pragma unroll
                for (int i = 0; i < 4; ++i) v[i] = s_out[(ck * 4 + i) * 133 + d];
                __builtin_nontemporal_store(v, (f32x4*)(out + ((size_t)b * Dd + d) * Nn + np + ck * 4));
            }
        }
    }
}

extern "C" void kernel_launch(void* const* d_in, const int* in_sizes, int n_in,
                              void* d_out, int out_size, void* d_ws, size_t ws_size,
                              hipStream_t stream) {
    const float* feature = (const float*)d_in[0];
    const int*   neigh   = (const int*)d_in[1];
    const float* w1 = (const float*)d_in[2];
    const float* g1 = (const float*)d_in[3];
    const float* b1 = (const float*)d_in[4];
    const float* m1 = (const float*)d_in[5];
    const float* v1 = (const float*)d_in[6];
    const float* w2 = (const float*)d_in[7];
    const float* g2 = (const float*)d_in[8];
    const float* b2 = (const float*)d_in[9];
    const float* m2 = (const float*)d_in[10];
    const float* v2 = (const float*)d_in[11];
    const float* w3 = (const float*)d_in[12];
    const float* g3 = (const float*)d_in[13];
    const float* b3 = (const float*)d_in[14];
    const float* m3 = (const float*)d_in[15];
    const float* v3 = (const float*)d_in[16];
    float* out = (float*)d_out;

    const size_t SZ_G1 = (size_t)Bb * Nn * 64 * 2;        // 20,971,520 B
    const size_t SZ_FT = (size_t)Bb * Nn * 64 * 2;        // 20,971,520 B

    char* ws = (char*)d_ws;
    unsigned short* G1  = (unsigned short*)ws;
    unsigned short* f_t = (unsigned short*)(ws + SZ_G1);
    char* wbase = ws + SZ_G1 + SZ_FT;

    unsigned short* w1s = (unsigned short*)wbase;
    unsigned short* w2s = (unsigned short*)(wbase + 8192);
    unsigned short* w3s = (unsigned short*)(wbase + 24576);
    float* sh1 = (float*)(wbase + 40960);
    float* sh2 = (float*)(wbase + 41216);
    float* sh3 = (float*)(wbase + 41728);

    prep_weights<<<80, 256, 0, stream>>>(w1, g1, b1, m1, v1, w2, g2, b2, m2, v2,
                                         w3, g3, b3, m3, v3, w1s, w2s, w3s, sh1, sh2, sh3);
    passA<<<Bb * 640, 256, 0, stream>>>(feature, w1s, sh1, G1, f_t);
    passB<<<(Bb * TPB) / G, 256, 0, stream>>>(G1, f_t, neigh, w2s, w3s,
                                              sh2, sh3, out);
}